// Round 14
// baseline (293.399 us; speedup 1.0000x reference)
//
#include <hip/hip_runtime.h>
#include <math.h>

#define NN   50000
#define NE   800000
#define FEATD 128
#define SED  16
#define HD   64
#define NCLS 10
#define NLAY 3
#define NG   500

// two-level counting sort params
#define CHUNK 4096
#define NCH   ((NE + CHUNK - 1) / CHUNK)  // 196
#define CBSH  9
#define CB    ((NN + (1 << CBSH) - 1) >> CBSH)  // 98

typedef short  v8s __attribute__((ext_vector_type(8)));
typedef float  v4f __attribute__((ext_vector_type(4)));

// ---- bf16 helpers ---------------------------------------------------------
__device__ inline unsigned short f2bf(float f){
    unsigned int u = __float_as_uint(f);
    u += 0x7fffu + ((u >> 16) & 1u);
    return (unsigned short)(u >> 16);
}
__device__ inline unsigned int pack2bf(float a, float b){
    return (unsigned int)f2bf(a) | ((unsigned int)f2bf(b) << 16);
}
__device__ inline float bf_lo(unsigned int p){ return __uint_as_float(p << 16); }
__device__ inline float bf_hi(unsigned int p){ return __uint_as_float(p & 0xffff0000u); }

// fast tanh via v_exp (accuracy ~1e-7 rel, far below bf16 storage error)
__device__ inline float fast_tanh(float x){
    float ax = fabsf(x);
    float t  = __expf(-2.f * ax);
    float r  = (1.f - t) / (1.f + t);
    return copysignf(r, x);
}

// ---------------- fused prep: weight transposes + coarse hist + gbuf zero --
// All weights emitted in MFMA FRAGMENT ORDER: W[k][col] lands at
//   ((((col/16)*NKO + k/32)*4 + (k/8)%4)*16 + col%16)*8 + k%8
// so a wave's v8s fragment load is base + lane*16B (fully coalesced).
// blocks [0,264): wprep (incl. preWF K=128 and embWF K=16->32 zero-pad);
// [264,264+NCH): coarse_hist; rest: zero gbuf.
__global__ __launch_bounds__(256) void k_prep(
        const float* __restrict__ gcn_W, const float* __restrict__ gin_W1,
        const float* __restrict__ gin_W2, const float* __restrict__ whp_W,
        const float* __restrict__ pre_W, const float* __restrict__ emb_W,
        unsigned short* __restrict__ gcnWF, unsigned short* __restrict__ W1F,
        unsigned short* __restrict__ W2F,  unsigned short* __restrict__ whpWF,
        unsigned short* __restrict__ preWF, unsigned short* __restrict__ embWF,
        const int* __restrict__ dst, int* __restrict__ ghist,
        float* __restrict__ gbuf)
{
    __shared__ int h[CB];
    int b = blockIdx.x;
    if (b < 264){
        int i = b*256 + threadIdx.x;
        if (i < 12288){            // gcn: 3 x [64][64], NKO=2
            int li = i / 4096, r = i % 4096, k = r >> 6, col = r & 63;
            int dfr = (((((col>>4)*2 + (k>>5))*4 + ((k>>3)&3))*16 + (col&15))<<3) + (k&7);
            gcnWF[li*4096 + dfr] = f2bf(gcn_W[li*4096 + k*64 + col]);
        } else if (i < 36864){     // W1: 3 x [128][64], NKO=4
            int j = i - 12288; int li = j / 8192, r = j % 8192, k = r >> 6, col = r & 63;
            int dfr = (((((col>>4)*4 + (k>>5))*4 + ((k>>3)&3))*16 + (col&15))<<3) + (k&7);
            W1F[li*8192 + dfr] = f2bf(gin_W1[li*8192 + k*64 + col]);
        } else if (i < 49152){     // W2: 3 x [64][64], NKO=2
            int j = i - 36864; int li = j / 4096, r = j % 4096, k = r >> 6, col = r & 63;
            int dfr = (((((col>>4)*2 + (k>>5))*4 + ((k>>3)&3))*16 + (col&15))<<3) + (k&7);
            W2F[li*4096 + dfr] = f2bf(gin_W2[li*4096 + k*64 + col]);
        } else if (i < 57344){     // whp: [128][64], NKO=4
            int j = i - 49152; int k = j >> 6, col = j & 63;
            int dfr = (((((col>>4)*4 + (k>>5))*4 + ((k>>3)&3))*16 + (col&15))<<3) + (k&7);
            whpWF[dfr] = f2bf(whp_W[k*64 + col]);
        } else if (i < 65536){     // pre: [128][64], NKO=4
            int j = i - 57344; int k = j >> 6, col = j & 63;
            int dfr = (((((col>>4)*4 + (k>>5))*4 + ((k>>3)&3))*16 + (col&15))<<3) + (k&7);
            preWF[dfr] = f2bf(pre_W[k*64 + col]);
        } else if (i < 67584){     // emb: [16][64] zero-padded to K=32, NKO=1
            int j = i - 65536; int k = j >> 6, col = j & 63;   // k in [0,32)
            int dfr = (((((col>>4)*1 + (k>>5))*4 + ((k>>3)&3))*16 + (col&15))<<3) + (k&7);
            embWF[dfr] = (k < 16) ? f2bf(emb_W[k*64 + col]) : (unsigned short)0;
        }
    } else if (b < 264 + NCH){
        int c = b - 264;
        for (int i = threadIdx.x; i < CB; i += 256) h[i] = 0;
        __syncthreads();
        int base = c * CHUNK;
        int end  = base + CHUNK; if (end > NE) end = NE;
        for (int i = base + threadIdx.x; i < end; i += 256)
            atomicAdd(&h[dst[i] >> CBSH], 1);
        __syncthreads();
        for (int i = threadIdx.x; i < CB; i += 256)
            ghist[(size_t)c * CB + i] = h[i];
    } else {
        int i = (b - 264 - NCH)*256 + threadIdx.x;
        if (i < NG*64) gbuf[i] = 0.f;
    }
}

// LDS-staged scan of ghist (196*98 ints = 77KB LDS); single-block kernel.
__global__ __launch_bounds__(256) void coarse_scan(int* __restrict__ ghist){
    __shared__ int sh[NCH * CB];
    __shared__ int sc[256];
    int t = threadIdx.x;
    for (int i = t; i < NCH * CB; i += 256) sh[i] = ghist[i];
    __syncthreads();
    int run = 0;
    if (t < CB){
        for (int c = 0; c < NCH; c++){
            int v = sh[c*CB + t];
            sh[c*CB + t] = run;
            run += v;
        }
    }
    sc[t] = (t < CB) ? run : 0;
    __syncthreads();
    for (int d = 1; d < 256; d <<= 1){
        int u = (t >= d) ? sc[t-d] : 0;
        __syncthreads();
        sc[t] += u;
        __syncthreads();
    }
    int bstart = (t == 0) ? 0 : sc[t-1];
    if (t < CB){
        for (int c = 0; c < NCH; c++) sh[c*CB + t] += bstart;
    }
    __syncthreads();
    for (int i = t; i < NCH * CB; i += 256) ghist[i] = sh[i];
}

// ---------------- fused: bin_lds (blocks [0,NCH)) + pre_emb MFMA (rest) ----
__global__ __launch_bounds__(256) void bin_pre(
        const int* __restrict__ src, const int* __restrict__ dstp,
        const int* __restrict__ ghist, unsigned int* __restrict__ ebuf,
        const float* __restrict__ x, const unsigned short* __restrict__ preWF,
        const float* __restrict__ preb,
        const float* __restrict__ s, const unsigned short* __restrict__ embWF,
        const float* __restrict__ embb,
        unsigned short* __restrict__ xcb, int n)
{
    extern __shared__ char smem[];
    int t = threadIdx.x;
    if (blockIdx.x < NCH){
        // ---- bin_lds ----
        unsigned int* lbuf  = (unsigned int*)smem;
        unsigned int* lbuf2 = lbuf + CHUNK;
        int* hist   = (int*)(lbuf2 + CHUNK);
        int* lstart = hist + CB;
        int* cursor = lstart + CB;
        int* gbase  = cursor + CB;
        int* sc     = gbase + CB;
        int c = blockIdx.x;
        for (int i = t; i < CB; i += 256){
            hist[i] = 0;
            gbase[i] = ghist[(size_t)c*CB + i];
        }
        __syncthreads();
        int base = c * CHUNK;
        int nend = base + CHUNK; if (nend > NE) nend = NE;
        nend -= base;
        for (int i = t; i < nend; i += 256){
            int d = dstp[base + i];
            lbuf[i] = (unsigned int)src[base + i] | ((unsigned int)d << 16);
            atomicAdd(&hist[d >> CBSH], 1);
        }
        __syncthreads();
        sc[t] = (t < CB) ? hist[t] : 0;
        __syncthreads();
        for (int d = 1; d < 256; d <<= 1){
            int u = (t >= d) ? sc[t-d] : 0;
            __syncthreads();
            sc[t] += u;
            __syncthreads();
        }
        if (t < CB){
            lstart[t] = sc[t] - hist[t];
            cursor[t] = sc[t] - hist[t];
        }
        __syncthreads();
        for (int i = t; i < nend; i += 256){
            unsigned int u = lbuf[i];
            int b = (int)(u >> 16) >> CBSH;
            int p = atomicAdd(&cursor[b], 1);
            lbuf2[p] = u;
        }
        __syncthreads();
        for (int p = t; p < nend; p += 256){
            unsigned int u = lbuf2[p];
            int b = (int)(u >> 16) >> CBSH;
            ebuf[gbase[b] + (p - lstart[b])] = u;
        }
    } else {
        // ---- pre_emb via MFMA ----
        unsigned short* ash = (unsigned short*)smem;   // 16*136 (x tile bf16)
        unsigned short* bsh = ash + 16*136;            // 16*40  (s tile, K pad 32)
        unsigned short* xsh = bsh + 16*40;             // 16*136 (output tile)
        int pblk  = blockIdx.x - NCH;
        int rbase = pblk * 16;
        int w = t >> 6, l = t & 63;
        int m = l & 15, q = l >> 4;
        int col = w*16 + m;
        for (int i = t; i < 16*40; i += 256) bsh[i] = 0;
#pragma unroll
        for (int j = 0; j < 2; j++){
            int cid = t*2 + j;
            int row = cid >> 5, c4 = cid & 31;
            int orow = rbase + row;
            float4 v = make_float4(0.f, 0.f, 0.f, 0.f);
            if (orow < n) v = *(const float4*)(x + (size_t)orow * 128 + c4*4);
            *(unsigned int*)(&ash[row*136 + c4*4])     = pack2bf(v.x, v.y);
            *(unsigned int*)(&ash[row*136 + c4*4 + 2]) = pack2bf(v.z, v.w);
        }
        __syncthreads();
        {
            int row = t >> 4, k = t & 15;
            int orow = rbase + row;
            bsh[row*40 + k] = (orow < n) ? f2bf(s[(size_t)orow*16 + k]) : (unsigned short)0;
        }
        __syncthreads();
        {
            v8s ap[4];
#pragma unroll
            for (int ko = 0; ko < 4; ko++)
                ap[ko] = *(const v8s*)(&ash[m*136 + ko*32 + q*8]);
            v4f accp = {0.f, 0.f, 0.f, 0.f};
#pragma unroll
            for (int ko = 0; ko < 4; ko++){
                v8s b = *(const v8s*)(preWF + (size_t)((w*4 + ko)*64 + l) * 8);
                accp = __builtin_amdgcn_mfma_f32_16x16x32_bf16(ap[ko], b, accp, 0, 0, 0);
            }
            v8s ae = *(const v8s*)(&bsh[m*40 + q*8]);
            v8s be = *(const v8s*)(embWF + (size_t)(w*64 + l) * 8);
            v4f acce = {0.f, 0.f, 0.f, 0.f};
            acce = __builtin_amdgcn_mfma_f32_16x16x32_bf16(ae, be, acce, 0, 0, 0);
            float bvp = preb[col];
            float bve = embb[col];
#pragma unroll
            for (int r = 0; r < 4; r++){
                xsh[(q*4 + r)*136 + col]      = f2bf(accp[r] + bvp);
                xsh[(q*4 + r)*136 + 64 + col] = f2bf(acce[r] + bve);
            }
        }
        __syncthreads();
        {
            int row = t >> 4, ch = t & 15;
            int orow = rbase + row;
            if (orow < n)
                *(uint4*)(xcb + (size_t)orow * 128 + ch*8) =
                    *(const uint4*)(&xsh[row*136 + ch*8]);
        }
    }
}

__global__ __launch_bounds__(256) void scatter_all(
        const unsigned int* __restrict__ ebuf, const int* __restrict__ ghist,
        int* __restrict__ off, float* __restrict__ dinv,
        int* __restrict__ csr, int n){
    __shared__ int lcnt[512];
    __shared__ int lex[512];
    __shared__ int sc[256];
    int t = threadIdx.x, b = blockIdx.x;
    int n0 = b << CBSH;
    int nn = n - n0; if (nn > 512) nn = 512;
    int lo = ghist[b];
    int hi = (b + 1 < CB) ? ghist[b + 1] : NE;
    lcnt[t] = 0; lcnt[t + 256] = 0;
    __syncthreads();
    for (int j = lo + t; j < hi; j += 256)
        atomicAdd(&lcnt[(int)(ebuf[j] >> 16) - n0], 1);
    __syncthreads();
    int c0 = lcnt[2*t], c1 = lcnt[2*t+1];
    sc[t] = c0 + c1;
    __syncthreads();
    for (int d = 1; d < 256; d <<= 1){
        int u = (t >= d) ? sc[t-d] : 0;
        __syncthreads();
        sc[t] += u;
        __syncthreads();
    }
    int bse = sc[t] - (c0 + c1);
    lex[2*t]   = bse;
    lex[2*t+1] = bse + c0;
    __syncthreads();
    for (int i = t; i < nn; i += 256){
        off[n0 + i]  = lo + lex[i];
        dinv[n0 + i] = rsqrtf((float)lcnt[i] + 1.0f);
    }
    if (b == 0 && t == 0) off[n] = NE;
    __syncthreads();
    for (int j = lo + t; j < hi; j += 256){
        unsigned int u = ebuf[j];
        int d = (int)(u >> 16) - n0;
        int p = atomicAdd(&lex[d], 1);
        csr[lo + p] = (int)(u & 0xffffu);
    }
}

// ---------------- fused per-layer: merged agg + GIN MLP + GCN linear -------
// Block = 16 nodes, 4 waves. Phase 1 (agg): wave w handles nodes w*4..w*4+3
// as TWO INTERLEAVED PAIRS -- two independent csr->gather streams in flight
// per wave (R13 counters: 4 serial chains/wave left the pipes idle at 53us;
// VALUBusy 23%, MfmaUtil 1.7%). Issue order is explicit: csrA, csrB,
// gathersA, gathersB, consume A, consume B. Branches are wave-uniform.
// Per-node edge order and fma tree unchanged -> bit-exact vs R13.
// Phase 2: quadrant-split MFMA MLP (R12 body). NN % 16 == 0.
__global__ __launch_bounds__(256) void agg_mlp(
        const unsigned int* __restrict__ xcb_cur,
        const float* __restrict__ dinv,
        const int* __restrict__ off, const int* __restrict__ csr,
        const unsigned short* __restrict__ W1F,     // frag order, K=128
        const float* __restrict__ b1,
        const unsigned short* __restrict__ W2F,     // frag order, K=64
        const float* __restrict__ b2,
        const unsigned short* __restrict__ gcnWF,   // frag order, K=64
        const float* __restrict__ gcnb,
        unsigned short* __restrict__ xcb_nxt,
        const unsigned short* __restrict__ whpWF,   // frag order, K=128
        const float* __restrict__ whpb,
        const int* __restrict__ batch,
        float* __restrict__ gbuf,
        int do_whp, int n)
{
    __shared__ unsigned short ash[16 * 136];   // hpre tile (agg output)
    __shared__ unsigned short bsh[16 * 72];    // ub tile (agg output)
    __shared__ unsigned short hsh[16 * 72];    // GEMM1 output
    __shared__ unsigned short xsh[16 * 136];   // [x_new|s_new] tile
    __shared__ float gacc[8 * 64];
    int tid = threadIdx.x;
    int w = tid >> 6, l = tid & 63;
    int m = l & 15, q = l >> 4;
    int rbase = blockIdx.x * 16;
    int col   = w*16 + m;

    // ---- phase 1: aggregation, 2 node-pairs per wave, dual-stream ----
    for (int p = 0; p < 2; p++){
        int lrA = w*4 + p*2, lrB = lrA + 1;
        int nodeA = __builtin_amdgcn_readfirstlane(rbase + lrA);
        int nodeB = __builtin_amdgcn_readfirstlane(rbase + lrB);
        int begA = off[nodeA], endA = off[nodeA+1];
        int begB = off[nodeB], endB = off[nodeB+1];
        unsigned int psA = xcb_cur[(size_t)nodeA*64 + l];
        unsigned int psB = xcb_cur[(size_t)nodeB*64 + l];
        float sA0 = bf_lo(psA), sA1 = bf_hi(psA);
        float sB0 = bf_lo(psB), sB1 = bf_hi(psB);
        float aA0 = sA0, aA1 = sA1, gA0 = 0.f, gA1 = 0.f;
        float aB0 = sB0, aB1 = sB1, gB0 = 0.f, gB1 = 0.f;
        int eA = begA, eB = begB;
        while ((eA + 8 <= endA) || (eB + 8 <= endB)){
            bool dA = (eA + 8 <= endA);
            bool dB = (eB + 8 <= endB);
            int ia[8], ib[8];
            unsigned int pa[8], pb[8];
            float da[8], db[8];
            if (dA){
#pragma unroll
                for (int j = 0; j < 8; j++) ia[j] = csr[eA + j];
            }
            if (dB){
#pragma unroll
                for (int j = 0; j < 8; j++) ib[j] = csr[eB + j];
            }
            if (dA){
#pragma unroll
                for (int j = 0; j < 8; j++) pa[j] = xcb_cur[(size_t)ia[j]*64 + l];
#pragma unroll
                for (int j = 0; j < 8; j++) da[j] = dinv[ia[j]];
            }
            if (dB){
#pragma unroll
                for (int j = 0; j < 8; j++) pb[j] = xcb_cur[(size_t)ib[j]*64 + l];
#pragma unroll
                for (int j = 0; j < 8; j++) db[j] = dinv[ib[j]];
            }
            if (dA){
                float v0 = bf_lo(pa[0]), v1 = bf_lo(pa[1]), v2 = bf_lo(pa[2]), v3 = bf_lo(pa[3]);
                float v4 = bf_lo(pa[4]), v5 = bf_lo(pa[5]), v6 = bf_lo(pa[6]), v7 = bf_lo(pa[7]);
                float w0 = bf_hi(pa[0]), w1 = bf_hi(pa[1]), w2 = bf_hi(pa[2]), w3 = bf_hi(pa[3]);
                float w4 = bf_hi(pa[4]), w5 = bf_hi(pa[5]), w6 = bf_hi(pa[6]), w7 = bf_hi(pa[7]);
                aA0 += ((v0 + v1) + (v2 + v3)) + ((v4 + v5) + (v6 + v7));
                aA1 += ((w0 + w1) + (w2 + w3)) + ((w4 + w5) + (w6 + w7));
                float ga = fmaf(da[0], v0, fmaf(da[1], v1, fmaf(da[2], v2, da[3]*v3)));
                float gb = fmaf(da[4], v4, fmaf(da[5], v5, fmaf(da[6], v6, da[7]*v7)));
                gA0 += ga + gb;
                float gc = fmaf(da[0], w0, fmaf(da[1], w1, fmaf(da[2], w2, da[3]*w3)));
                float gd = fmaf(da[4], w4, fmaf(da[5], w5, fmaf(da[6], w6, da[7]*w7)));
                gA1 += gc + gd;
                eA += 8;
            }
            if (dB){
                float v0 = bf_lo(pb[0]), v1 = bf_lo(pb[1]), v2 = bf_lo(pb[2]), v3 = bf_lo(pb[3]);
                float v4 = bf_lo(pb[4]), v5 = bf_lo(pb[5]), v6 = bf_lo(pb[6]), v7 = bf_lo(pb[7]);
                float w0 = bf_hi(pb[0]), w1 = bf_hi(pb[1]), w2 = bf_hi(pb[2]), w3 = bf_hi(pb[3]);
                float w4 = bf_hi(pb[4]), w5 = bf_hi(pb[5]), w6 = bf_hi(pb[6]), w7 = bf_hi(pb[7]);
                aB0 += ((v0 + v1) + (v2 + v3)) + ((v4 + v5) + (v6 + v7));
                aB1 += ((w0 + w1) + (w2 + w3)) + ((w4 + w5) + (w6 + w7));
                float ga = fmaf(db[0], v0, fmaf(db[1], v1, fmaf(db[2], v2, db[3]*v3)));
                float gb = fmaf(db[4], v4, fmaf(db[5], v5, fmaf(db[6], v6, db[7]*v7)));
                gB0 += ga + gb;
                float gc = fmaf(db[0], w0, fmaf(db[1], w1, fmaf(db[2], w2, db[3]*w3)));
                float gd = fmaf(db[4], w4, fmaf(db[5], w5, fmaf(db[6], w6, db[7]*w7)));
                gB1 += gc + gd;
                eB += 8;
            }
        }
        // tails (A then B): 4-edge then scalar, same fma trees as before
        for (; eA + 4 <= endA; eA += 4){
            int s0 = csr[eA], s1 = csr[eA+1], s2 = csr[eA+2], s3 = csr[eA+3];
            unsigned int p0 = xcb_cur[(size_t)s0*64 + l];
            unsigned int p1 = xcb_cur[(size_t)s1*64 + l];
            unsigned int p2 = xcb_cur[(size_t)s2*64 + l];
            unsigned int p3 = xcb_cur[(size_t)s3*64 + l];
            float d0 = dinv[s0], d1 = dinv[s1], d2 = dinv[s2], d3 = dinv[s3];
            float v0 = bf_lo(p0), v1 = bf_lo(p1), v2 = bf_lo(p2), v3 = bf_lo(p3);
            float w0 = bf_hi(p0), w1 = bf_hi(p1), w2 = bf_hi(p2), w3 = bf_hi(p3);
            aA0 += (v0 + v1) + (v2 + v3);
            aA1 += (w0 + w1) + (w2 + w3);
            gA0 = fmaf(d0, v0, fmaf(d1, v1, fmaf(d2, v2, fmaf(d3, v3, gA0))));
            gA1 = fmaf(d0, w0, fmaf(d1, w1, fmaf(d2, w2, fmaf(d3, w3, gA1))));
        }
        for (; eA < endA; eA++){
            int s0 = csr[eA];
            unsigned int p0 = xcb_cur[(size_t)s0*64 + l];
            float d0 = dinv[s0];
            float v0 = bf_lo(p0), w0 = bf_hi(p0);
            aA0 += v0; aA1 += w0;
            gA0 = fmaf(d0, v0, gA0);
            gA1 = fmaf(d0, w0, gA1);
        }
        for (; eB + 4 <= endB; eB += 4){
            int s0 = csr[eB], s1 = csr[eB+1], s2 = csr[eB+2], s3 = csr[eB+3];
            unsigned int p0 = xcb_cur[(size_t)s0*64 + l];
            unsigned int p1 = xcb_cur[(size_t)s1*64 + l];
            unsigned int p2 = xcb_cur[(size_t)s2*64 + l];
            unsigned int p3 = xcb_cur[(size_t)s3*64 + l];
            float d0 = dinv[s0], d1 = dinv[s1], d2 = dinv[s2], d3 = dinv[s3];
            float v0 = bf_lo(p0), v1 = bf_lo(p1), v2 = bf_lo(p2), v3 = bf_lo(p3);
            float w0 = bf_hi(p0), w1 = bf_hi(p1), w2 = bf_hi(p2), w3 = bf_hi(p3);
            aB0 += (v0 + v1) + (v2 + v3);
            aB1 += (w0 + w1) + (w2 + w3);
            gB0 = fmaf(d0, v0, fmaf(d1, v1, fmaf(d2, v2, fmaf(d3, v3, gB0))));
            gB1 = fmaf(d0, w0, fmaf(d1, w1, fmaf(d2, w2, fmaf(d3, w3, gB1))));
        }
        for (; eB < endB; eB++){
            int s0 = csr[eB];
            unsigned int p0 = xcb_cur[(size_t)s0*64 + l];
            float d0 = dinv[s0];
            float v0 = bf_lo(p0), w0 = bf_hi(p0);
            aB0 += v0; aB1 += w0;
            gB0 = fmaf(d0, v0, gB0);
            gB1 = fmaf(d0, w0, gB1);
        }
        *(unsigned int*)(&ash[lrA*136 + 2*l]) = pack2bf(aA0, aA1);
        *(unsigned int*)(&ash[lrB*136 + 2*l]) = pack2bf(aB0, aB1);
        if (l >= 32){   // lanes 32..63 hold s_prev cols (64..127)
            float diA = dinv[nodeA], diB = dinv[nodeB];
            *(unsigned int*)(&bsh[lrA*72 + 2*(l - 32)]) =
                pack2bf(fmaf(diA, gA0, diA*diA*sA0), fmaf(diA, gA1, diA*diA*sA1));
            *(unsigned int*)(&bsh[lrB*72 + 2*(l - 32)]) =
                pack2bf(fmaf(diB, gB0, diB*diB*sB0), fmaf(diB, gB1, diB*diB*sB1));
        }
    }
    int bmin = 0, span = 0;
    bool useLds = false;
    if (do_whp){
        int rmax = rbase + 15; if (rmax > n - 1) rmax = n - 1;
        bmin = batch[rbase];
        span = batch[rmax] - bmin + 1;
        useLds = (span <= 8);
        if (useLds)
            for (int i = tid; i < span * 64; i += 256) gacc[i] = 0.f;
    }
    __syncthreads();

    // ---- phase 2: MFMA MLP (quadrant w) ----
    // GEMM3: s_new = tanh(ub @ gcnW + b) -> xsh cols 64+
    {
        v8s a3[2];
#pragma unroll
        for (int ko = 0; ko < 2; ko++)
            a3[ko] = *(const v8s*)(&bsh[m*72 + ko*32 + q*8]);
        v4f acc = {0.f, 0.f, 0.f, 0.f};
#pragma unroll
        for (int ko = 0; ko < 2; ko++){
            v8s b = *(const v8s*)(gcnWF + (size_t)((w*2 + ko)*64 + l) * 8);
            acc = __builtin_amdgcn_mfma_f32_16x16x32_bf16(a3[ko], b, acc, 0, 0, 0);
        }
        float bv = gcnb[col];
#pragma unroll
        for (int r = 0; r < 4; r++)
            xsh[(q*4 + r)*136 + 64 + col] = f2bf(fast_tanh(acc[r] + bv));
    }
    // GEMM1: h = relu(hpre @ W1 + b1) -> hsh
    {
        v8s a[4];
#pragma unroll
        for (int ko = 0; ko < 4; ko++)
            a[ko] = *(const v8s*)(&ash[m*136 + ko*32 + q*8]);
        v4f acc = {0.f, 0.f, 0.f, 0.f};
#pragma unroll
        for (int ko = 0; ko < 4; ko++){
            v8s b = *(const v8s*)(W1F + (size_t)((w*4 + ko)*64 + l) * 8);
            acc = __builtin_amdgcn_mfma_f32_16x16x32_bf16(a[ko], b, acc, 0, 0, 0);
        }
        float bv = b1[col];
#pragma unroll
        for (int r = 0; r < 4; r++)
            hsh[(q*4 + r)*72 + col] = f2bf(fmaxf(acc[r] + bv, 0.f));
    }
    __syncthreads();
    // GEMM2: x_new = relu(h @ W2 + b2) -> xsh cols 0..63
    {
        v8s a2[2];
#pragma unroll
        for (int ko = 0; ko < 2; ko++)
            a2[ko] = *(const v8s*)(&hsh[m*72 + ko*32 + q*8]);
        v4f acc = {0.f, 0.f, 0.f, 0.f};
#pragma unroll
        for (int ko = 0; ko < 2; ko++){
            v8s b = *(const v8s*)(W2F + (size_t)((w*2 + ko)*64 + l) * 8);
            acc = __builtin_amdgcn_mfma_f32_16x16x32_bf16(a2[ko], b, acc, 0, 0, 0);
        }
        float bv = b2[col];
#pragma unroll
        for (int r = 0; r < 4; r++)
            xsh[(q*4 + r)*136 + col] = f2bf(fmaxf(acc[r] + bv, 0.f));
    }
    __syncthreads();   // xsh complete

    if (!do_whp){
        int row = tid >> 4, ch = tid & 15;
        int orow = rbase + row;
        if (orow < n)
            *(uint4*)(xcb_nxt + (size_t)orow * 128 + ch*8) =
                *(const uint4*)(&xsh[row*136 + ch*8]);
    } else {
        // GEMM4: xw = [x_new|s_new] @ whpW + b, pooled by graph
        v8s a4[4];
#pragma unroll
        for (int ko = 0; ko < 4; ko++)
            a4[ko] = *(const v8s*)(&xsh[m*136 + ko*32 + q*8]);
        int bb[4];
#pragma unroll
        for (int r = 0; r < 4; r++){
            int orow = rbase + q*4 + r;
            bb[r] = (orow < n) ? batch[orow] : -1;
        }
        v4f acc = {0.f, 0.f, 0.f, 0.f};
#pragma unroll
        for (int ko = 0; ko < 4; ko++){
            v8s b = *(const v8s*)(whpWF + (size_t)((w*4 + ko)*64 + l) * 8);
            acc = __builtin_amdgcn_mfma_f32_16x16x32_bf16(a4[ko], b, acc, 0, 0, 0);
        }
        float bv = whpb[col];
#pragma unroll
        for (int r = 0; r < 4; r++){
            if (bb[r] >= 0){
                float val = acc[r] + bv;
                if (useLds) atomicAdd(&gacc[(bb[r] - bmin) * 64 + col], val);
                else        atomicAdd(&gbuf[(size_t)bb[r] * 64 + col], val);
            }
        }
        __syncthreads();
        if (useLds){
            for (int i = tid; i < span * 64; i += 256)
                atomicAdd(&gbuf[(size_t)(bmin + (i >> 6)) * 64 + (i & 63)], gacc[i]);
        }
    }
}

// ---------------- head ----------------------------------------------------
__global__ __launch_bounds__(256) void head_kernel(
        const float* __restrict__ g, const float* __restrict__ postW,
        const float* __restrict__ postb, const float* __restrict__ roW,
        const float* __restrict__ rob, float* __restrict__ out, int ngraph)
{
    int gr = __builtin_amdgcn_readfirstlane(blockIdx.x * 4 + (threadIdx.x >> 6));
    int lane = threadIdx.x & 63;
    if (gr >= ngraph) return;
    float gv = g[(size_t)gr*64 + lane];
    float t = postb[lane];
    for (int k = 0; k < 64; k++){
        float a = __shfl(gv, k);
        t = fmaf(a, postW[k*64 + lane], t);
    }
    t = fmaxf(t, 0.f);
    float lg = (lane < NCLS) ? rob[lane] : 0.f;
    for (int k = 0; k < 64; k++){
        float a = __shfl(t, k);
        float w = (lane < NCLS) ? roW[k*NCLS + lane] : 0.f;
        lg = fmaf(a, w, lg);
    }
    float m = (lane < NCLS) ? lg : -INFINITY;
#pragma unroll
    for (int d = 1; d < 16; d <<= 1) m = fmaxf(m, __shfl_xor(m, d, 16));
    float ex = (lane < NCLS) ? expf(lg - m) : 0.f;
    float ssum = ex;
#pragma unroll
    for (int d = 1; d < 16; d <<= 1) ssum += __shfl_xor(ssum, d, 16);
    if (lane < NCLS) out[(size_t)gr*NCLS + lane] = lg - m - logf(ssum);
}

// ---------------- launch --------------------------------------------------
extern "C" void kernel_launch(void* const* d_in, const int* in_sizes, int n_in,
                              void* d_out, int out_size, void* d_ws, size_t ws_size,
                              hipStream_t stream) {
    const float* x      = (const float*)d_in[0];
    const float* s      = (const float*)d_in[1];
    const int*   ei     = (const int*)d_in[2];    // int32
    const int*   batch  = (const int*)d_in[3];    // int32
    const float* pre_W  = (const float*)d_in[4];
    const float* pre_b  = (const float*)d_in[5];
    const float* emb_W  = (const float*)d_in[6];
    const float* emb_b  = (const float*)d_in[7];
    const float* gin_W1 = (const float*)d_in[8];
    const float* gin_b1 = (const float*)d_in[9];
    const float* gin_W2 = (const float*)d_in[10];
    const float* gin_b2 = (const float*)d_in[11];
    const float* gcn_W  = (const float*)d_in[12];
    const float* gcn_b  = (const float*)d_in[13];
    const float* whp_W  = (const float*)d_in[14];
    const float* whp_b  = (const float*)d_in[15];
    const float* post_W = (const float*)d_in[16];
    const float* post_b = (const float*)d_in[17];
    const float* ro_W   = (const float*)d_in[18];
    const float* ro_b   = (const float*)d_in[19];
    float* out = (float*)d_out;

    char* w = (char*)d_ws;
    auto alloc = [&](size_t bytes) -> void* {
        void* p = (void*)w;
        w += (bytes + 255) & ~(size_t)255;
        return p;
    };
    int*   off   = (int*)  alloc((size_t)(NN+1) * 4);
    int*   csr   = (int*)  alloc((size_t)NE * 4);
    int*   ghist = (int*)  alloc((size_t)NCH * CB * 4);
    unsigned int* ebuf = (unsigned int*)alloc((size_t)NE * 4);
    float* dinv = (float*)alloc((size_t)NN * 4);
    unsigned short* xcb0 = (unsigned short*)alloc((size_t)NN * 128 * 2);
    unsigned short* xcb1 = (unsigned short*)alloc((size_t)NN * 128 * 2);
    float* gbuf = (float*)alloc((size_t)NG * 64 * 4);
    unsigned short* gcnWF = (unsigned short*)alloc((size_t)3 * 4096 * 2);
    unsigned short* W1F   = (unsigned short*)alloc((size_t)3 * 8192 * 2);
    unsigned short* W2F   = (unsigned short*)alloc((size_t)3 * 4096 * 2);
    unsigned short* whpWF = (unsigned short*)alloc((size_t)8192 * 2);
    unsigned short* preWF = (unsigned short*)alloc((size_t)8192 * 2);
    unsigned short* embWF = (unsigned short*)alloc((size_t)2048 * 2);

    const int B   = 256;
    const int GT  = (NN + 15) / 16;        // 3125 (16-row tiles)
    const int GZB = (NG*64 + 255) / 256;   // 126

    // fused prep (wprep-frag + coarse_hist + gbuf zero), then scan, then
    // fused bin+pre_emb-MFMA (dynamic LDS = 38912B), then scatter.
    k_prep<<<264 + NCH + GZB, B, 0, stream>>>(gcn_W, gin_W1, gin_W2, whp_W,
                                              pre_W, emb_W,
                                              gcnWF, W1F, W2F, whpWF,
                                              preWF, embWF,
                                              ei + NE, ghist, gbuf);
    coarse_scan<<<1, B, 0, stream>>>(ghist);
    bin_pre<<<NCH + GT, B, 38912, stream>>>(ei, ei + NE, ghist, ebuf,
                                            x, preWF, pre_b, s, embWF, emb_b,
                                            xcb0, NN);
    scatter_all<<<CB, B, 0, stream>>>(ebuf, ghist, off, dinv, csr, NN);

    for (int i = 0; i < NLAY; i++){
        unsigned short* cur = (i & 1) ? xcb1 : xcb0;
        unsigned short* nxt = (i & 1) ? xcb0 : xcb1;
        agg_mlp<<<GT, B, 0, stream>>>((const unsigned int*)cur, dinv, off, csr,
                                      W1F + (size_t)i*8192, gin_b1 + i*64,
                                      W2F + (size_t)i*4096, gin_b2 + i*64,
                                      gcnWF + (size_t)i*4096, gcn_b + i*64,
                                      nxt,
                                      whpWF, whp_b, batch, gbuf,
                                      (i == NLAY - 1) ? 1 : 0, NN);
    }

    // pool fused into last agg_mlp; head reads gbuf
    head_kernel<<<(NG + 3)/4, B, 0, stream>>>(gbuf, post_W, post_b, ro_W, ro_b, out, NG);
}

// Round 15
// 287.140 us; speedup vs baseline: 1.0218x; 1.0218x over previous
//
#include <hip/hip_runtime.h>
#include <math.h>

#define NN   50000
#define NE   800000
#define FEATD 128
#define SED  16
#define HD   64
#define NCLS 10
#define NLAY 3
#define NG   500

// two-level counting sort params
#define CHUNK 4096
#define NCH   ((NE + CHUNK - 1) / CHUNK)  // 196
#define CBSH  9
#define CB    ((NN + (1 << CBSH) - 1) >> CBSH)  // 98

typedef short  v8s __attribute__((ext_vector_type(8)));
typedef float  v4f __attribute__((ext_vector_type(4)));

// ---- bf16 helpers ---------------------------------------------------------
__device__ inline unsigned short f2bf(float f){
    unsigned int u = __float_as_uint(f);
    u += 0x7fffu + ((u >> 16) & 1u);
    return (unsigned short)(u >> 16);
}
__device__ inline unsigned int pack2bf(float a, float b){
    return (unsigned int)f2bf(a) | ((unsigned int)f2bf(b) << 16);
}
__device__ inline float bf_lo(unsigned int p){ return __uint_as_float(p << 16); }
__device__ inline float bf_hi(unsigned int p){ return __uint_as_float(p & 0xffff0000u); }

// fast tanh via v_exp (accuracy ~1e-7 rel, far below bf16 storage error)
__device__ inline float fast_tanh(float x){
    float ax = fabsf(x);
    float t  = __expf(-2.f * ax);
    float r  = (1.f - t) / (1.f + t);
    return copysignf(r, x);
}

// ---------------- fused prep: weight transposes + coarse hist + gbuf zero --
// All weights emitted in MFMA FRAGMENT ORDER: W[k][col] lands at
//   ((((col/16)*NKO + k/32)*4 + (k/8)%4)*16 + col%16)*8 + k%8
// so a wave's v8s fragment load is base + lane*16B (fully coalesced).
// blocks [0,264): wprep (incl. preWF K=128 and embWF K=16->32 zero-pad);
// [264,264+NCH): coarse_hist; rest: zero gbuf.
__global__ __launch_bounds__(256) void k_prep(
        const float* __restrict__ gcn_W, const float* __restrict__ gin_W1,
        const float* __restrict__ gin_W2, const float* __restrict__ whp_W,
        const float* __restrict__ pre_W, const float* __restrict__ emb_W,
        unsigned short* __restrict__ gcnWF, unsigned short* __restrict__ W1F,
        unsigned short* __restrict__ W2F,  unsigned short* __restrict__ whpWF,
        unsigned short* __restrict__ preWF, unsigned short* __restrict__ embWF,
        const int* __restrict__ dst, int* __restrict__ ghist,
        float* __restrict__ gbuf)
{
    __shared__ int h[CB];
    int b = blockIdx.x;
    if (b < 264){
        int i = b*256 + threadIdx.x;
        if (i < 12288){            // gcn: 3 x [64][64], NKO=2
            int li = i / 4096, r = i % 4096, k = r >> 6, col = r & 63;
            int dfr = (((((col>>4)*2 + (k>>5))*4 + ((k>>3)&3))*16 + (col&15))<<3) + (k&7);
            gcnWF[li*4096 + dfr] = f2bf(gcn_W[li*4096 + k*64 + col]);
        } else if (i < 36864){     // W1: 3 x [128][64], NKO=4
            int j = i - 12288; int li = j / 8192, r = j % 8192, k = r >> 6, col = r & 63;
            int dfr = (((((col>>4)*4 + (k>>5))*4 + ((k>>3)&3))*16 + (col&15))<<3) + (k&7);
            W1F[li*8192 + dfr] = f2bf(gin_W1[li*8192 + k*64 + col]);
        } else if (i < 49152){     // W2: 3 x [64][64], NKO=2
            int j = i - 36864; int li = j / 4096, r = j % 4096, k = r >> 6, col = r & 63;
            int dfr = (((((col>>4)*2 + (k>>5))*4 + ((k>>3)&3))*16 + (col&15))<<3) + (k&7);
            W2F[li*4096 + dfr] = f2bf(gin_W2[li*4096 + k*64 + col]);
        } else if (i < 57344){     // whp: [128][64], NKO=4
            int j = i - 49152; int k = j >> 6, col = j & 63;
            int dfr = (((((col>>4)*4 + (k>>5))*4 + ((k>>3)&3))*16 + (col&15))<<3) + (k&7);
            whpWF[dfr] = f2bf(whp_W[k*64 + col]);
        } else if (i < 65536){     // pre: [128][64], NKO=4
            int j = i - 57344; int k = j >> 6, col = j & 63;
            int dfr = (((((col>>4)*4 + (k>>5))*4 + ((k>>3)&3))*16 + (col&15))<<3) + (k&7);
            preWF[dfr] = f2bf(pre_W[k*64 + col]);
        } else if (i < 67584){     // emb: [16][64] zero-padded to K=32, NKO=1
            int j = i - 65536; int k = j >> 6, col = j & 63;   // k in [0,32)
            int dfr = (((((col>>4)*1 + (k>>5))*4 + ((k>>3)&3))*16 + (col&15))<<3) + (k&7);
            embWF[dfr] = (k < 16) ? f2bf(emb_W[k*64 + col]) : (unsigned short)0;
        }
    } else if (b < 264 + NCH){
        int c = b - 264;
        for (int i = threadIdx.x; i < CB; i += 256) h[i] = 0;
        __syncthreads();
        int base = c * CHUNK;
        int end  = base + CHUNK; if (end > NE) end = NE;
        for (int i = base + threadIdx.x; i < end; i += 256)
            atomicAdd(&h[dst[i] >> CBSH], 1);
        __syncthreads();
        for (int i = threadIdx.x; i < CB; i += 256)
            ghist[(size_t)c * CB + i] = h[i];
    } else {
        int i = (b - 264 - NCH)*256 + threadIdx.x;
        if (i < NG*64) gbuf[i] = 0.f;
    }
}

// LDS-staged scan of ghist (196*98 ints = 77KB LDS); single-block kernel.
__global__ __launch_bounds__(256) void coarse_scan(int* __restrict__ ghist){
    __shared__ int sh[NCH * CB];
    __shared__ int sc[256];
    int t = threadIdx.x;
    for (int i = t; i < NCH * CB; i += 256) sh[i] = ghist[i];
    __syncthreads();
    int run = 0;
    if (t < CB){
        for (int c = 0; c < NCH; c++){
            int v = sh[c*CB + t];
            sh[c*CB + t] = run;
            run += v;
        }
    }
    sc[t] = (t < CB) ? run : 0;
    __syncthreads();
    for (int d = 1; d < 256; d <<= 1){
        int u = (t >= d) ? sc[t-d] : 0;
        __syncthreads();
        sc[t] += u;
        __syncthreads();
    }
    int bstart = (t == 0) ? 0 : sc[t-1];
    if (t < CB){
        for (int c = 0; c < NCH; c++) sh[c*CB + t] += bstart;
    }
    __syncthreads();
    for (int i = t; i < NCH * CB; i += 256) ghist[i] = sh[i];
}

// ---------------- fused: bin_lds (blocks [0,NCH)) + pre_emb MFMA (rest) ----
__global__ __launch_bounds__(256) void bin_pre(
        const int* __restrict__ src, const int* __restrict__ dstp,
        const int* __restrict__ ghist, unsigned int* __restrict__ ebuf,
        const float* __restrict__ x, const unsigned short* __restrict__ preWF,
        const float* __restrict__ preb,
        const float* __restrict__ s, const unsigned short* __restrict__ embWF,
        const float* __restrict__ embb,
        unsigned short* __restrict__ xcb, int n)
{
    extern __shared__ char smem[];
    int t = threadIdx.x;
    if (blockIdx.x < NCH){
        // ---- bin_lds ----
        unsigned int* lbuf  = (unsigned int*)smem;
        unsigned int* lbuf2 = lbuf + CHUNK;
        int* hist   = (int*)(lbuf2 + CHUNK);
        int* lstart = hist + CB;
        int* cursor = lstart + CB;
        int* gbase  = cursor + CB;
        int* sc     = gbase + CB;
        int c = blockIdx.x;
        for (int i = t; i < CB; i += 256){
            hist[i] = 0;
            gbase[i] = ghist[(size_t)c*CB + i];
        }
        __syncthreads();
        int base = c * CHUNK;
        int nend = base + CHUNK; if (nend > NE) nend = NE;
        nend -= base;
        for (int i = t; i < nend; i += 256){
            int d = dstp[base + i];
            lbuf[i] = (unsigned int)src[base + i] | ((unsigned int)d << 16);
            atomicAdd(&hist[d >> CBSH], 1);
        }
        __syncthreads();
        sc[t] = (t < CB) ? hist[t] : 0;
        __syncthreads();
        for (int d = 1; d < 256; d <<= 1){
            int u = (t >= d) ? sc[t-d] : 0;
            __syncthreads();
            sc[t] += u;
            __syncthreads();
        }
        if (t < CB){
            lstart[t] = sc[t] - hist[t];
            cursor[t] = sc[t] - hist[t];
        }
        __syncthreads();
        for (int i = t; i < nend; i += 256){
            unsigned int u = lbuf[i];
            int b = (int)(u >> 16) >> CBSH;
            int p = atomicAdd(&cursor[b], 1);
            lbuf2[p] = u;
        }
        __syncthreads();
        for (int p = t; p < nend; p += 256){
            unsigned int u = lbuf2[p];
            int b = (int)(u >> 16) >> CBSH;
            ebuf[gbase[b] + (p - lstart[b])] = u;
        }
    } else {
        // ---- pre_emb via MFMA ----
        unsigned short* ash = (unsigned short*)smem;   // 16*136 (x tile bf16)
        unsigned short* bsh = ash + 16*136;            // 16*40  (s tile, K pad 32)
        unsigned short* xsh = bsh + 16*40;             // 16*136 (output tile)
        int pblk  = blockIdx.x - NCH;
        int rbase = pblk * 16;
        int w = t >> 6, l = t & 63;
        int m = l & 15, q = l >> 4;
        int col = w*16 + m;
        for (int i = t; i < 16*40; i += 256) bsh[i] = 0;
#pragma unroll
        for (int j = 0; j < 2; j++){
            int cid = t*2 + j;
            int row = cid >> 5, c4 = cid & 31;
            int orow = rbase + row;
            float4 v = make_float4(0.f, 0.f, 0.f, 0.f);
            if (orow < n) v = *(const float4*)(x + (size_t)orow * 128 + c4*4);
            *(unsigned int*)(&ash[row*136 + c4*4])     = pack2bf(v.x, v.y);
            *(unsigned int*)(&ash[row*136 + c4*4 + 2]) = pack2bf(v.z, v.w);
        }
        __syncthreads();
        {
            int row = t >> 4, k = t & 15;
            int orow = rbase + row;
            bsh[row*40 + k] = (orow < n) ? f2bf(s[(size_t)orow*16 + k]) : (unsigned short)0;
        }
        __syncthreads();
        {
            v8s ap[4];
#pragma unroll
            for (int ko = 0; ko < 4; ko++)
                ap[ko] = *(const v8s*)(&ash[m*136 + ko*32 + q*8]);
            v4f accp = {0.f, 0.f, 0.f, 0.f};
#pragma unroll
            for (int ko = 0; ko < 4; ko++){
                v8s b = *(const v8s*)(preWF + (size_t)((w*4 + ko)*64 + l) * 8);
                accp = __builtin_amdgcn_mfma_f32_16x16x32_bf16(ap[ko], b, accp, 0, 0, 0);
            }
            v8s ae = *(const v8s*)(&bsh[m*40 + q*8]);
            v8s be = *(const v8s*)(embWF + (size_t)(w*64 + l) * 8);
            v4f acce = {0.f, 0.f, 0.f, 0.f};
            acce = __builtin_amdgcn_mfma_f32_16x16x32_bf16(ae, be, acce, 0, 0, 0);
            float bvp = preb[col];
            float bve = embb[col];
#pragma unroll
            for (int r = 0; r < 4; r++){
                xsh[(q*4 + r)*136 + col]      = f2bf(accp[r] + bvp);
                xsh[(q*4 + r)*136 + 64 + col] = f2bf(acce[r] + bve);
            }
        }
        __syncthreads();
        {
            int row = t >> 4, ch = t & 15;
            int orow = rbase + row;
            if (orow < n)
                *(uint4*)(xcb + (size_t)orow * 128 + ch*8) =
                    *(const uint4*)(&xsh[row*136 + ch*8]);
        }
    }
}

__global__ __launch_bounds__(256) void scatter_all(
        const unsigned int* __restrict__ ebuf, const int* __restrict__ ghist,
        int* __restrict__ off, float* __restrict__ dinv,
        int* __restrict__ csr, int n){
    __shared__ int lcnt[512];
    __shared__ int lex[512];
    __shared__ int sc[256];
    int t = threadIdx.x, b = blockIdx.x;
    int n0 = b << CBSH;
    int nn = n - n0; if (nn > 512) nn = 512;
    int lo = ghist[b];
    int hi = (b + 1 < CB) ? ghist[b + 1] : NE;
    lcnt[t] = 0; lcnt[t + 256] = 0;
    __syncthreads();
    for (int j = lo + t; j < hi; j += 256)
        atomicAdd(&lcnt[(int)(ebuf[j] >> 16) - n0], 1);
    __syncthreads();
    int c0 = lcnt[2*t], c1 = lcnt[2*t+1];
    sc[t] = c0 + c1;
    __syncthreads();
    for (int d = 1; d < 256; d <<= 1){
        int u = (t >= d) ? sc[t-d] : 0;
        __syncthreads();
        sc[t] += u;
        __syncthreads();
    }
    int bse = sc[t] - (c0 + c1);
    lex[2*t]   = bse;
    lex[2*t+1] = bse + c0;
    __syncthreads();
    for (int i = t; i < nn; i += 256){
        off[n0 + i]  = lo + lex[i];
        dinv[n0 + i] = rsqrtf((float)lcnt[i] + 1.0f);
    }
    if (b == 0 && t == 0) off[n] = NE;
    __syncthreads();
    for (int j = lo + t; j < hi; j += 256){
        unsigned int u = ebuf[j];
        int d = (int)(u >> 16) - n0;
        int p = atomicAdd(&lex[d], 1);
        csr[lo + p] = (int)(u & 0xffffu);
    }
}

// ---------------- fused per-layer: merged agg + GIN MLP + GCN linear -------
// Block = 16 nodes, 4 waves. Phase 1 (agg): wave w runs the proven 8-edge
// unrolled gather body for nodes rbase+4w..+3, writing pack2bf results
// directly into the ash/bsh LDS tiles. Phase 2: quadrant-split MFMA MLP.
// NOTE (R14): dual-stream ILP restructure was NULL and cost occupancy --
// the agg phase is L2-request-throughput bound (~1.6M line-reqs/layer,
// FETCH 84MB from per-XCD L2 thrash of the 12.8MB xcb), not latency bound.
// This is the R13 form: simplest code at the same ceiling. NN % 16 == 0.
__global__ __launch_bounds__(256) void agg_mlp(
        const unsigned int* __restrict__ xcb_cur,
        const float* __restrict__ dinv,
        const int* __restrict__ off, const int* __restrict__ csr,
        const unsigned short* __restrict__ W1F,     // frag order, K=128
        const float* __restrict__ b1,
        const unsigned short* __restrict__ W2F,     // frag order, K=64
        const float* __restrict__ b2,
        const unsigned short* __restrict__ gcnWF,   // frag order, K=64
        const float* __restrict__ gcnb,
        unsigned short* __restrict__ xcb_nxt,
        const unsigned short* __restrict__ whpWF,   // frag order, K=128
        const float* __restrict__ whpb,
        const int* __restrict__ batch,
        float* __restrict__ gbuf,
        int do_whp, int n)
{
    __shared__ unsigned short ash[16 * 136];   // hpre tile (agg output)
    __shared__ unsigned short bsh[16 * 72];    // ub tile (agg output)
    __shared__ unsigned short hsh[16 * 72];    // GEMM1 output
    __shared__ unsigned short xsh[16 * 136];   // [x_new|s_new] tile
    __shared__ float gacc[8 * 64];
    int tid = threadIdx.x;
    int w = tid >> 6, l = tid & 63;
    int m = l & 15, q = l >> 4;
    int rbase = blockIdx.x * 16;
    int col   = w*16 + m;

    // ---- phase 1: aggregation (4 nodes per wave) ----
    for (int vi = 0; vi < 4; vi++){
        int lrow = w*4 + vi;
        int node = __builtin_amdgcn_readfirstlane(rbase + lrow);
        int beg = off[node], end = off[node+1];
        unsigned int ps = xcb_cur[(size_t)node*64 + l];
        float s0f = bf_lo(ps), s1f = bf_hi(ps);
        float a0 = s0f, a1 = s1f;
        float g0 = 0.f, g1 = 0.f;
        int e = beg;
        for (; e + 8 <= end; e += 8){
            int s0 = csr[e],   s1 = csr[e+1], s2 = csr[e+2], s3 = csr[e+3];
            int s4 = csr[e+4], s5 = csr[e+5], s6 = csr[e+6], s7 = csr[e+7];
            unsigned int p0 = xcb_cur[(size_t)s0*64 + l];
            unsigned int p1 = xcb_cur[(size_t)s1*64 + l];
            unsigned int p2 = xcb_cur[(size_t)s2*64 + l];
            unsigned int p3 = xcb_cur[(size_t)s3*64 + l];
            unsigned int p4 = xcb_cur[(size_t)s4*64 + l];
            unsigned int p5 = xcb_cur[(size_t)s5*64 + l];
            unsigned int p6 = xcb_cur[(size_t)s6*64 + l];
            unsigned int p7 = xcb_cur[(size_t)s7*64 + l];
            float d0 = dinv[s0], d1 = dinv[s1], d2 = dinv[s2], d3 = dinv[s3];
            float d4 = dinv[s4], d5 = dinv[s5], d6 = dinv[s6], d7 = dinv[s7];
            float v0 = bf_lo(p0), v1 = bf_lo(p1), v2 = bf_lo(p2), v3 = bf_lo(p3);
            float v4 = bf_lo(p4), v5 = bf_lo(p5), v6 = bf_lo(p6), v7 = bf_lo(p7);
            float w0 = bf_hi(p0), w1 = bf_hi(p1), w2 = bf_hi(p2), w3 = bf_hi(p3);
            float w4 = bf_hi(p4), w5 = bf_hi(p5), w6 = bf_hi(p6), w7 = bf_hi(p7);
            a0 += ((v0 + v1) + (v2 + v3)) + ((v4 + v5) + (v6 + v7));
            a1 += ((w0 + w1) + (w2 + w3)) + ((w4 + w5) + (w6 + w7));
            float ga = fmaf(d0, v0, fmaf(d1, v1, fmaf(d2, v2, d3*v3)));
            float gb = fmaf(d4, v4, fmaf(d5, v5, fmaf(d6, v6, d7*v7)));
            g0 += ga + gb;
            float gc = fmaf(d0, w0, fmaf(d1, w1, fmaf(d2, w2, d3*w3)));
            float gd = fmaf(d4, w4, fmaf(d5, w5, fmaf(d6, w6, d7*w7)));
            g1 += gc + gd;
        }
        for (; e + 4 <= end; e += 4){
            int s0 = csr[e], s1 = csr[e+1], s2 = csr[e+2], s3 = csr[e+3];
            unsigned int p0 = xcb_cur[(size_t)s0*64 + l];
            unsigned int p1 = xcb_cur[(size_t)s1*64 + l];
            unsigned int p2 = xcb_cur[(size_t)s2*64 + l];
            unsigned int p3 = xcb_cur[(size_t)s3*64 + l];
            float d0 = dinv[s0], d1 = dinv[s1], d2 = dinv[s2], d3 = dinv[s3];
            float v0 = bf_lo(p0), v1 = bf_lo(p1), v2 = bf_lo(p2), v3 = bf_lo(p3);
            float w0 = bf_hi(p0), w1 = bf_hi(p1), w2 = bf_hi(p2), w3 = bf_hi(p3);
            a0 += (v0 + v1) + (v2 + v3);
            a1 += (w0 + w1) + (w2 + w3);
            g0 = fmaf(d0, v0, fmaf(d1, v1, fmaf(d2, v2, fmaf(d3, v3, g0))));
            g1 = fmaf(d0, w0, fmaf(d1, w1, fmaf(d2, w2, fmaf(d3, w3, g1))));
        }
        for (; e < end; e++){
            int s0 = csr[e];
            unsigned int p0 = xcb_cur[(size_t)s0*64 + l];
            float d0 = dinv[s0];
            float v0 = bf_lo(p0), w0 = bf_hi(p0);
            a0 += v0; a1 += w0;
            g0 = fmaf(d0, v0, g0);
            g1 = fmaf(d0, w0, g1);
        }
        *(unsigned int*)(&ash[lrow*136 + 2*l]) = pack2bf(a0, a1);
        if (l >= 32){   // lanes 32..63 hold s_prev cols (64..127)
            float di = dinv[node];
            float u0 = fmaf(di, g0, di*di*s0f);
            float u1 = fmaf(di, g1, di*di*s1f);
            *(unsigned int*)(&bsh[lrow*72 + 2*(l - 32)]) = pack2bf(u0, u1);
        }
    }
    int bmin = 0, span = 0;
    bool useLds = false;
    if (do_whp){
        int rmax = rbase + 15; if (rmax > n - 1) rmax = n - 1;
        bmin = batch[rbase];
        span = batch[rmax] - bmin + 1;
        useLds = (span <= 8);
        if (useLds)
            for (int i = tid; i < span * 64; i += 256) gacc[i] = 0.f;
    }
    __syncthreads();

    // ---- phase 2: MFMA MLP (quadrant w) ----
    // GEMM3: s_new = tanh(ub @ gcnW + b) -> xsh cols 64+
    {
        v8s a3[2];
#pragma unroll
        for (int ko = 0; ko < 2; ko++)
            a3[ko] = *(const v8s*)(&bsh[m*72 + ko*32 + q*8]);
        v4f acc = {0.f, 0.f, 0.f, 0.f};
#pragma unroll
        for (int ko = 0; ko < 2; ko++){
            v8s b = *(const v8s*)(gcnWF + (size_t)((w*2 + ko)*64 + l) * 8);
            acc = __builtin_amdgcn_mfma_f32_16x16x32_bf16(a3[ko], b, acc, 0, 0, 0);
        }
        float bv = gcnb[col];
#pragma unroll
        for (int r = 0; r < 4; r++)
            xsh[(q*4 + r)*136 + 64 + col] = f2bf(fast_tanh(acc[r] + bv));
    }
    // GEMM1: h = relu(hpre @ W1 + b1) -> hsh
    {
        v8s a[4];
#pragma unroll
        for (int ko = 0; ko < 4; ko++)
            a[ko] = *(const v8s*)(&ash[m*136 + ko*32 + q*8]);
        v4f acc = {0.f, 0.f, 0.f, 0.f};
#pragma unroll
        for (int ko = 0; ko < 4; ko++){
            v8s b = *(const v8s*)(W1F + (size_t)((w*4 + ko)*64 + l) * 8);
            acc = __builtin_amdgcn_mfma_f32_16x16x32_bf16(a[ko], b, acc, 0, 0, 0);
        }
        float bv = b1[col];
#pragma unroll
        for (int r = 0; r < 4; r++)
            hsh[(q*4 + r)*72 + col] = f2bf(fmaxf(acc[r] + bv, 0.f));
    }
    __syncthreads();
    // GEMM2: x_new = relu(h @ W2 + b2) -> xsh cols 0..63
    {
        v8s a2[2];
#pragma unroll
        for (int ko = 0; ko < 2; ko++)
            a2[ko] = *(const v8s*)(&hsh[m*72 + ko*32 + q*8]);
        v4f acc = {0.f, 0.f, 0.f, 0.f};
#pragma unroll
        for (int ko = 0; ko < 2; ko++){
            v8s b = *(const v8s*)(W2F + (size_t)((w*2 + ko)*64 + l) * 8);
            acc = __builtin_amdgcn_mfma_f32_16x16x32_bf16(a2[ko], b, acc, 0, 0, 0);
        }
        float bv = b2[col];
#pragma unroll
        for (int r = 0; r < 4; r++)
            xsh[(q*4 + r)*136 + col] = f2bf(fmaxf(acc[r] + bv, 0.f));
    }
    __syncthreads();   // xsh complete

    if (!do_whp){
        int row = tid >> 4, ch = tid & 15;
        int orow = rbase + row;
        if (orow < n)
            *(uint4*)(xcb_nxt + (size_t)orow * 128 + ch*8) =
                *(const uint4*)(&xsh[row*136 + ch*8]);
    } else {
        // GEMM4: xw = [x_new|s_new] @ whpW + b, pooled by graph
        v8s a4[4];
#pragma unroll
        for (int ko = 0; ko < 4; ko++)
            a4[ko] = *(const v8s*)(&xsh[m*136 + ko*32 + q*8]);
        int bb[4];
#pragma unroll
        for (int r = 0; r < 4; r++){
            int orow = rbase + q*4 + r;
            bb[r] = (orow < n) ? batch[orow] : -1;
        }
        v4f acc = {0.f, 0.f, 0.f, 0.f};
#pragma unroll
        for (int ko = 0; ko < 4; ko++){
            v8s b = *(const v8s*)(whpWF + (size_t)((w*4 + ko)*64 + l) * 8);
            acc = __builtin_amdgcn_mfma_f32_16x16x32_bf16(a4[ko], b, acc, 0, 0, 0);
        }
        float bv = whpb[col];
#pragma unroll
        for (int r = 0; r < 4; r++){
            if (bb[r] >= 0){
                float val = acc[r] + bv;
                if (useLds) atomicAdd(&gacc[(bb[r] - bmin) * 64 + col], val);
                else        atomicAdd(&gbuf[(size_t)bb[r] * 64 + col], val);
            }
        }
        __syncthreads();
        if (useLds){
            for (int i = tid; i < span * 64; i += 256)
                atomicAdd(&gbuf[(size_t)(bmin + (i >> 6)) * 64 + (i & 63)], gacc[i]);
        }
    }
}

// ---------------- head ----------------------------------------------------
__global__ __launch_bounds__(256) void head_kernel(
        const float* __restrict__ g, const float* __restrict__ postW,
        const float* __restrict__ postb, const float* __restrict__ roW,
        const float* __restrict__ rob, float* __restrict__ out, int ngraph)
{
    int gr = __builtin_amdgcn_readfirstlane(blockIdx.x * 4 + (threadIdx.x >> 6));
    int lane = threadIdx.x & 63;
    if (gr >= ngraph) return;
    float gv = g[(size_t)gr*64 + lane];
    float t = postb[lane];
    for (int k = 0; k < 64; k++){
        float a = __shfl(gv, k);
        t = fmaf(a, postW[k*64 + lane], t);
    }
    t = fmaxf(t, 0.f);
    float lg = (lane < NCLS) ? rob[lane] : 0.f;
    for (int k = 0; k < 64; k++){
        float a = __shfl(t, k);
        float w = (lane < NCLS) ? roW[k*NCLS + lane] : 0.f;
        lg = fmaf(a, w, lg);
    }
    float m = (lane < NCLS) ? lg : -INFINITY;
#pragma unroll
    for (int d = 1; d < 16; d <<= 1) m = fmaxf(m, __shfl_xor(m, d, 16));
    float ex = (lane < NCLS) ? expf(lg - m) : 0.f;
    float ssum = ex;
#pragma unroll
    for (int d = 1; d < 16; d <<= 1) ssum += __shfl_xor(ssum, d, 16);
    if (lane < NCLS) out[(size_t)gr*NCLS + lane] = lg - m - logf(ssum);
}

// ---------------- launch --------------------------------------------------
extern "C" void kernel_launch(void* const* d_in, const int* in_sizes, int n_in,
                              void* d_out, int out_size, void* d_ws, size_t ws_size,
                              hipStream_t stream) {
    const float* x      = (const float*)d_in[0];
    const float* s      = (const float*)d_in[1];
    const int*   ei     = (const int*)d_in[2];    // int32
    const int*   batch  = (const int*)d_in[3];    // int32
    const float* pre_W  = (const float*)d_in[4];
    const float* pre_b  = (const float*)d_in[5];
    const float* emb_W  = (const float*)d_in[6];
    const float* emb_b  = (const float*)d_in[7];
    const float* gin_W1 = (const float*)d_in[8];
    const float* gin_b1 = (const float*)d_in[9];
    const float* gin_W2 = (const float*)d_in[10];
    const float* gin_b2 = (const float*)d_in[11];
    const float* gcn_W  = (const float*)d_in[12];
    const float* gcn_b  = (const float*)d_in[13];
    const float* whp_W  = (const float*)d_in[14];
    const float* whp_b  = (const float*)d_in[15];
    const float* post_W = (const float*)d_in[16];
    const float* post_b = (const float*)d_in[17];
    const float* ro_W   = (const float*)d_in[18];
    const float* ro_b   = (const float*)d_in[19];
    float* out = (float*)d_out;

    char* w = (char*)d_ws;
    auto alloc = [&](size_t bytes) -> void* {
        void* p = (void*)w;
        w += (bytes + 255) & ~(size_t)255;
        return p;
    };
    int*   off   = (int*)  alloc((size_t)(NN+1) * 4);
    int*   csr   = (int*)  alloc((size_t)NE * 4);
    int*   ghist = (int*)  alloc((size_t)NCH * CB * 4);
    unsigned int* ebuf = (unsigned int*)alloc((size_t)NE * 4);
    float* dinv = (float*)alloc((size_t)NN * 4);
    unsigned short* xcb0 = (unsigned short*)alloc((size_t)NN * 128 * 2);
    unsigned short* xcb1 = (unsigned short*)alloc((size_t)NN * 128 * 2);
    float* gbuf = (float*)alloc((size_t)NG * 64 * 4);
    unsigned short* gcnWF = (unsigned short*)alloc((size_t)3 * 4096 * 2);
    unsigned short* W1F   = (unsigned short*)alloc((size_t)3 * 8192 * 2);
    unsigned short* W2F   = (unsigned short*)alloc((size_t)3 * 4096 * 2);
    unsigned short* whpWF = (unsigned short*)alloc((size_t)8192 * 2);
    unsigned short* preWF = (unsigned short*)alloc((size_t)8192 * 2);
    unsigned short* embWF = (unsigned short*)alloc((size_t)2048 * 2);

    const int B   = 256;
    const int GT  = (NN + 15) / 16;        // 3125 (16-row tiles)
    const int GZB = (NG*64 + 255) / 256;   // 126

    // fused prep (wprep-frag + coarse_hist + gbuf zero), then scan, then
    // fused bin+pre_emb-MFMA (dynamic LDS = 38912B), then scatter.
    k_prep<<<264 + NCH + GZB, B, 0, stream>>>(gcn_W, gin_W1, gin_W2, whp_W,
                                              pre_W, emb_W,
                                              gcnWF, W1F, W2F, whpWF,
                                              preWF, embWF,
                                              ei + NE, ghist, gbuf);
    coarse_scan<<<1, B, 0, stream>>>(ghist);
    bin_pre<<<NCH + GT, B, 38912, stream>>>(ei, ei + NE, ghist, ebuf,
                                            x, preWF, pre_b, s, embWF, emb_b,
                                            xcb0, NN);
    scatter_all<<<CB, B, 0, stream>>>(ebuf, ghist, off, dinv, csr, NN);

    for (int i = 0; i < NLAY; i++){
        unsigned short* cur = (i & 1) ? xcb1 : xcb0;
        unsigned short* nxt = (i & 1) ? xcb0 : xcb1;
        agg_mlp<<<GT, B, 0, stream>>>((const unsigned int*)cur, dinv, off, csr,
                                      W1F + (size_t)i*8192, gin_b1 + i*64,
                                      W2F + (size_t)i*4096, gin_b2 + i*64,
                                      gcnWF + (size_t)i*4096, gcn_b + i*64,
                                      nxt,
                                      whpWF, whp_b, batch, gbuf,
                                      (i == NLAY - 1) ? 1 : 0, NN);
    }

    // pool fused into last agg_mlp; head reads gbuf
    head_kernel<<<(NG + 3)/4, B, 0, stream>>>(gbuf, post_W, post_b, ro_W, ro_b, out, NG);
}